// Round 1
// 197.559 us; speedup vs baseline: 1.0286x; 1.0286x over previous
//
#include <hip/hip_runtime.h>
#include <hip/hip_bf16.h>

// Problem constants
#define NB  2      // batch
#define CC  256    // channels
#define NHD 8      // heads
#define HD  32     // head dim
#define NT  4096   // tokens = H*W

typedef __bf16 bf16x8 __attribute__((ext_vector_type(8)));
typedef bf16x8 bf16x8_ma __attribute__((may_alias));
typedef __bf16 bf16x4 __attribute__((ext_vector_type(4)));
typedef bf16x4 bf16x4_ma __attribute__((may_alias));
typedef float  f32x4  __attribute__((ext_vector_type(4)));
typedef float  f32x16 __attribute__((ext_vector_type(16)));
typedef unsigned int u32x4 __attribute__((ext_vector_type(4)));

static __device__ __forceinline__ f32x4 zero4() {
    f32x4 z = {0.f, 0.f, 0.f, 0.f}; return z;
}
static __device__ __forceinline__ f32x16 zero16() {
    f32x16 z = {0.f,0.f,0.f,0.f,0.f,0.f,0.f,0.f,
                0.f,0.f,0.f,0.f,0.f,0.f,0.f,0.f};
    return z;
}

// q pre-scale: log2(e) / sqrt(32)
#define QSCALE 0.25505392421795654f

// v_cvt_pk_bf16_f32: dst.lo = bf16(lo), dst.hi = bf16(hi)  (no builtin on gfx950)
#define CVT_PK(dst, lo, hi_) \
    asm("v_cvt_pk_bf16_f32 %0, %1, %2" : "=v"(dst) : "v"(lo), "v"(hi_))
// v_permlane32_swap_b32: x[32:63] <-> y[0:31]
#define PLSWAP(x, y) \
    asm("v_permlane32_swap_b32 %0, %1" : "+v"(x), "+v"(y))

// ---------------------------------------------------------------------------
// ROUND 18: attack the VALU-bound softmax neck (VALUBusy 74%, MfmaUtil 13%).
// attn_k rewritten: swapped-operand 32x32 MFMA (S^T = K*Q^T) so each lane
// holds P for ONE query column; raw v_exp_f32 (1 instr, was ~5 via ocml);
// cvt_pk_bf16 (16/tile, was 32 scalar cvts); permlane32_swap (8/tile) builds
// the PV A-fragments fully in-register -> the per-tile LDS P round-trip
// (32 ds_write_b16 + 4 ds_read_b128) is GONE. l kept as f32 adds of
// pre-conversion p (numerics identical to R17). Seg-combine via small f32
// LDS tile in the epilogue only.
// ---------------------------------------------------------------------------

// ---------------------------------------------------------------------------
// Kernel 0: f32 -> bf16 convert, both weight arrays in one launch.
// ---------------------------------------------------------------------------
__global__ __launch_bounds__(256) void convw_k(const float* __restrict__ s1,
                                               __bf16* __restrict__ d1, int n1,
                                               const float* __restrict__ s2,
                                               __bf16* __restrict__ d2, int n2) {
    const int i = blockIdx.x * 256 + threadIdx.x;
    if (i < n1) d1[i] = (__bf16)s1[i];
    else if (i - n1 < n2) d2[i - n1] = (__bf16)s2[i - n1];
}

// ---------------------------------------------------------------------------
// Kernel 1: LDS-tiled transpose+convert x f32 [b][c][n] -> xt bf16 [b][n][c].
// ---------------------------------------------------------------------------
__global__ __launch_bounds__(256) void transpose_k(const float* __restrict__ x,
                                                   __bf16* __restrict__ xt) {
    __shared__ __bf16 T[64][65];
    const int tid = threadIdx.x;
    const int n0 = blockIdx.x * 64, c0 = blockIdx.y * 64, b = blockIdx.z;

#pragma unroll
    for (int rep = 0; rep < 16; ++rep) {
        const int e = rep * 256 + tid;
        const int cl = e >> 6, nl = e & 63;
        T[nl][cl] = (__bf16)x[((size_t)(b * CC + c0 + cl)) * NT + n0 + nl];
    }
    __syncthreads();
#pragma unroll
    for (int rep = 0; rep < 16; ++rep) {
        const int e = rep * 256 + tid;
        const int nl = e >> 6, cl = e & 63;
        xt[((size_t)(b * NT + n0 + nl)) * CC + c0 + cl] = T[nl][cl];
    }
}

// ---------------------------------------------------------------------------
// Kernel 2: QKV GEMM (MFMA). q pre-scaled by QSCALE. Packed q/k stores.
// qt/kt token-major [bh][n][32], vv d-major [bh][32][n].
// grid (NT/64, 768/64, NB), block 256.
// ---------------------------------------------------------------------------
__global__ __launch_bounds__(256) void qkv_k(const __bf16* __restrict__ wqkv,
                                             const __bf16* __restrict__ xt,
                                             __bf16* __restrict__ qt,
                                             __bf16* __restrict__ kt,
                                             __bf16* __restrict__ vv) {
    const int lane = threadIdx.x & 63, wv = threadIdx.x >> 6;
    const int g = lane >> 4, c16 = lane & 15;
    const int b    = blockIdx.z;
    const int o0   = blockIdx.y * 64 + wv * 16;
    const int tok0 = blockIdx.x * 64;

    const __bf16* arow = wqkv + (size_t)(o0 + c16) * CC + g * 8;
    const __bf16* brow = xt + ((size_t)(b * NT + tok0 + c16)) * CC + g * 8;

    f32x4 acc[4];
#pragma unroll
    for (int i = 0; i < 4; ++i) acc[i] = zero4();

#pragma unroll
    for (int k0 = 0; k0 < CC; k0 += 32) {
        bf16x8 a = *(const bf16x8_ma*)(arow + k0);
#pragma unroll
        for (int js = 0; js < 4; ++js) {
            bf16x8 bb = *(const bf16x8_ma*)(brow + (size_t)js * 16 * CC + k0);
            acc[js] = __builtin_amdgcn_mfma_f32_16x16x32_bf16(a, bb, acc[js], 0, 0, 0);
        }
    }

    const int reg = o0 >> 8;                 // 0=q, 1=k, 2=v (wave-uniform)
    const int oo0 = (o0 & 255) + g * 4;
    const int h   = oo0 >> 5;
    const int dd0 = oo0 & 31;
    const size_t bh = (size_t)(b * NHD + h);

#pragma unroll
    for (int js = 0; js < 4; ++js) {
        const int tok = tok0 + js * 16 + c16;
        if (reg == 0) {
            bf16x4 pk;
#pragma unroll
            for (int r = 0; r < 4; ++r) pk[r] = (__bf16)(acc[js][r] * QSCALE);
            *(bf16x4_ma*)(qt + (bh * NT + tok) * HD + dd0) = pk;
        } else if (reg == 1) {
            bf16x4 pk;
#pragma unroll
            for (int r = 0; r < 4; ++r) pk[r] = (__bf16)acc[js][r];
            *(bf16x4_ma*)(kt + (bh * NT + tok) * HD + dd0) = pk;
        } else {
#pragma unroll
            for (int r = 0; r < 4; ++r)
                vv[(bh * HD + dd0 + r) * NT + tok] = (__bf16)acc[js][r];
        }
    }
}

// ---------------------------------------------------------------------------
// Kernel 3: MFMA flash attention, 32x32 swapped-operand, in-register P.
// Block 256 = 4 waves: (qp, seg). Wave owns 32 queries x one j-half.
// Per 64-j tile: 4 K loads + 4 V loads (b128); 4 score MFMAs (S^T: rows=j,
// cols=q -> every lane's 16 P values share q=lane&31); 32 v_exp_f32;
// 32 f32 rs adds; 16 v_cvt_pk_bf16_f32; 8 v_permlane32_swap; 4 PV MFMAs.
// Zero LDS ops in the loop. Additive (O,l) combine across segs in epilogue.
// grid (NT/64, NB*NHD), block 256.
// ---------------------------------------------------------------------------
__global__ __launch_bounds__(256, 4) void attn_k(const __bf16* __restrict__ qt,
                                                 const __bf16* __restrict__ kt,
                                                 const __bf16* __restrict__ vv,
                                                 __bf16* __restrict__ ao) {
    __shared__ __align__(16) float Olds[2][32][36];   // [qp][d][q(+pad)] 9216 B
    __shared__ float llds[2][2][32];                  // [seg][qp][q]      512 B

    const int tid  = threadIdx.x;
    const int lane = tid & 63, wv = tid >> 6;          // wv 0..3
    const int qp = wv & 1, seg = wv >> 1;
    const int c32 = lane & 31, hi = lane >> 5;
    const int bh = blockIdx.y;
    const int b = bh >> 3, h = bh & 7;
    const int i0 = blockIdx.x * 64 + qp * 32;          // this wave: 32 queries

    const __bf16* qbase = qt + ((size_t)bh * NT + i0) * HD;
    const __bf16* kbase = kt + (size_t)bh * NT * HD;
    const __bf16* vbase = vv + (size_t)bh * HD * NT;

    // Q fragments (B operand of score MFMA): row=q=c32, k = kk*16 + hi*8 + e
    bf16x8 aq0 = *(const bf16x8_ma*)(qbase + (size_t)c32 * HD + hi * 8);
    bf16x8 aq1 = *(const bf16x8_ma*)(qbase + (size_t)c32 * HD + 16 + hi * 8);

    f32x16 oacc = zero16();      // D[q_row][d_col]: rows=q, cols=d=c32
    float rs = 0.f;              // per-lane partial l for q = c32

    const int j_begin = seg * (NT / 2);
    const int j_end   = j_begin + (NT / 2);

    for (int j0 = j_begin; j0 < j_end; j0 += 64) {
#pragma unroll
        for (int js = 0; js < 2; ++js) {
            const int jb = j0 + js * 32;
            // K fragments (A operand): row=j=c32, k = kk*16 + hi*8 + e
            bf16x8 bk0 = *(const bf16x8_ma*)(kbase + (size_t)(jb + c32) * HD + hi * 8);
            bf16x8 bk1 = *(const bf16x8_ma*)(kbase + (size_t)(jb + c32) * HD + 16 + hi * 8);
            // V fragments (B operand of PV): row=d=c32, k = j offset
            bf16x8 bv0 = *(const bf16x8_ma*)(vbase + (size_t)c32 * NT + jb + hi * 8);
            bf16x8 bv1 = *(const bf16x8_ma*)(vbase + (size_t)c32 * NT + jb + 16 + hi * 8);

            // S^T tile [32 j][32 q]: lane holds j_row=(r&3)+8*(r>>2)+4*hi, q=c32
            f32x16 s = __builtin_amdgcn_mfma_f32_32x32x16_bf16(bk0, aq0, zero16(), 0, 0, 0);
            s = __builtin_amdgcn_mfma_f32_32x32x16_bf16(bk1, aq1, s, 0, 0, 0);

            // p = exp2(s) (q pre-scaled by log2e/sqrt(d)); rs accumulates in f32
            float p[16];
#pragma unroll
            for (int r = 0; r < 16; ++r) {
                p[r] = __builtin_amdgcn_exp2f(s[r]);
                rs += p[r];
            }

            // pack pairs: pk[i] = bf16(p[2i]) | bf16(p[2i+1])<<16
            unsigned pk[8];
#pragma unroll
            for (int i = 0; i < 8; ++i) CVT_PK(pk[i], p[2 * i], p[2 * i + 1]);

            // permlane32_swap redistribution (T12 pairing): after these 4 swaps
            // {pk0..3} is the PV A-frag for j [jb, jb+16), {pk4..7} for [jb+16, jb+32)
            PLSWAP(pk[0], pk[2]);
            PLSWAP(pk[1], pk[3]);
            PLSWAP(pk[4], pk[6]);
            PLSWAP(pk[5], pk[7]);

            u32x4 a0 = {pk[0], pk[1], pk[2], pk[3]};
            u32x4 a1 = {pk[4], pk[5], pk[6], pk[7]};
            const bf16x8 ap0 = __builtin_bit_cast(bf16x8, a0);
            const bf16x8 ap1 = __builtin_bit_cast(bf16x8, a1);

            oacc = __builtin_amdgcn_mfma_f32_32x32x16_bf16(ap0, bv0, oacc, 0, 0, 0);
            oacc = __builtin_amdgcn_mfma_f32_32x32x16_bf16(ap1, bv1, oacc, 0, 0, 0);
        }
    }

    // complete per-query l: lane and lane^32 each summed half the j's of q=c32
    rs += __shfl_xor(rs, 32, 64);

    if (hi == 0) llds[seg][qp][c32] = rs;
    if (seg == 1) {
        // O rows q = 8*g4 + 4*hi + (r&3): contiguous 4 -> f32x4 stores [d][q]
#pragma unroll
        for (int g4 = 0; g4 < 4; ++g4) {
            f32x4 t = {oacc[4 * g4 + 0], oacc[4 * g4 + 1],
                       oacc[4 * g4 + 2], oacc[4 * g4 + 3]};
            *(f32x4*)&Olds[qp][c32][8 * g4 + 4 * hi] = t;
        }
    }
    __syncthreads();
    if (seg == 0) {
#pragma unroll
        for (int g4 = 0; g4 < 4; ++g4) {
            const int q0 = 8 * g4 + 4 * hi;
            const f32x4 oprev = *(const f32x4*)&Olds[qp][c32][q0];
#pragma unroll
            for (int r = 0; r < 4; ++r) {
                const int q = q0 + r;
                const float lt = llds[0][qp][q] + llds[1][qp][q];
                const float ov = oacc[4 * g4 + r] + oprev[r];
                ao[((size_t)(b * NT) + i0 + q) * CC + h * HD + c32] =
                    (__bf16)(ov / lt);
            }
        }
    }
}

// ---------------------------------------------------------------------------
// Kernel 4: proj GEMM + residual (MFMA), F32 output.
// grid (NT/64, CC/64, NB), block 256.
// ---------------------------------------------------------------------------
__global__ __launch_bounds__(256) void proj_k(const __bf16* __restrict__ wp,
                                              const __bf16* __restrict__ ao,
                                              const float* __restrict__ x,
                                              float* __restrict__ out) {
    const int lane = threadIdx.x & 63, wv = threadIdx.x >> 6;
    const int g = lane >> 4, c16 = lane & 15;
    const int b    = blockIdx.z;
    const int o0   = blockIdx.y * 64 + wv * 16;
    const int tok0 = blockIdx.x * 64;

    const __bf16* arow = wp + (size_t)(o0 + c16) * CC + g * 8;
    const __bf16* brow = ao + ((size_t)(b * NT + tok0 + c16)) * CC + g * 8;

    f32x4 acc[4];
#pragma unroll
    for (int i = 0; i < 4; ++i) acc[i] = zero4();

#pragma unroll
    for (int k0 = 0; k0 < CC; k0 += 32) {
        bf16x8 a = *(const bf16x8_ma*)(arow + k0);
#pragma unroll
        for (int js = 0; js < 4; ++js) {
            bf16x8 bb = *(const bf16x8_ma*)(brow + (size_t)js * 16 * CC + k0);
            acc[js] = __builtin_amdgcn_mfma_f32_16x16x32_bf16(a, bb, acc[js], 0, 0, 0);
        }
    }

#pragma unroll
    for (int js = 0; js < 4; ++js) {
        const int tok = tok0 + js * 16 + c16;
#pragma unroll
        for (int r = 0; r < 4; ++r) {
            const int o = o0 + g * 4 + r;
            const size_t idx = ((size_t)(b * CC + o)) * NT + tok;
            out[idx] = acc[js][r] + x[idx];
        }
    }
}

// ---------------------------------------------------------------------------
extern "C" void kernel_launch(void* const* d_in, const int* in_sizes, int n_in,
                              void* d_out, int out_size, void* d_ws, size_t ws_size,
                              hipStream_t stream) {
    const int SX  = NB * CC * NT;   // 2,097,152
    const int SW3 = 3 * CC * CC;    //   196,608
    const int SW1 = CC * CC;        //    65,536
    const size_t E = (size_t)SX;

    const float* x  = nullptr;
    const float* wq = nullptr;
    const float* wp = nullptr;
    for (int i = 0; i < n_in; ++i) {
        const int sz = in_sizes[i];
        if (sz == SX || sz == 2 * SX || sz == 4 * SX)           x  = (const float*)d_in[i];
        else if (sz == SW3 || sz == 2 * SW3 || sz == 4 * SW3)   wq = (const float*)d_in[i];
        else if (sz == SW1 || sz == 2 * SW1 || sz == 4 * SW1)   wp = (const float*)d_in[i];
    }
    if (!x || !wq || !wp) {
        x  = (const float*)d_in[0];
        wq = (const float*)d_in[1];
        wp = (const float*)d_in[2];
    }

    // Workspace (bf16 elements), 16.5 MB total (proven):
    __bf16* ws  = (__bf16*)d_ws;
    __bf16* wqb = ws;
    __bf16* wpb = wqb + SW3;
    __bf16* xt  = wpb + SW1;             // becomes ao after qkv_k
    __bf16* qt  = xt + E;
    __bf16* kt  = qt + E;
    __bf16* vv  = kt + E;
    __bf16* ao  = xt;

    float* out = (float*)d_out;

    convw_k<<<dim3((SW3 + SW1 + 255) / 256), 256, 0, stream>>>(wq, wqb, SW3, wp, wpb, SW1);
    transpose_k<<<dim3(NT / 64, CC / 64, NB), 256, 0, stream>>>(x, xt);
    qkv_k<<<dim3(NT / 64, (3 * CC) / 64, NB), 256, 0, stream>>>(wqb, xt, qt, kt, vv);
    attn_k<<<dim3(NT / 64, NB * NHD), 256, 0, stream>>>(qt, kt, vv, ao);
    proj_k<<<dim3(NT / 64, CC / 64, NB), 256, 0, stream>>>(wpb, ao, x, out);
}